// Round 6
// baseline (326.020 us; speedup 1.0000x reference)
//
#include <hip/hip_runtime.h>

#define NROWS 262144
#define KK 10
#define BB 3.0f
#define SROW 136                   // phase-3 row stride in f16 (16 chunks of 8 f16 + 1 pad chunk)
#define HS 80                      // phase-1/2 h row stride in f16 (8 payload chunks + 2 pad)
#define SEGF16 (16 * SROW)         // 2176 f16 = 4352 B per tile segment
#define SENT 0.54132485f           // ln(e-1): softplus(SENT) == 1.0 (boundary derivative)
#define W_TOTAL (NROWS / 32)       // total waves (each wave: 2 tiles = 32 rows)

typedef _Float16 v8h __attribute__((ext_vector_type(8)));
typedef _Float16 v4h __attribute__((ext_vector_type(4)));
typedef float v4f __attribute__((ext_vector_type(4)));

// d_ws layout: v8h frags: W0[4*64] | W1[2*4*64] | WC[2*16*64] ; then f32 slots[64]
#define W0_OFF 0
#define W1_OFF 256
#define WC_OFF 768
#define FRAG_TOTAL 2816
#define SLOTS_OFF (FRAG_TOTAL * 4)   // f32 units from ws base (FRAG_TOTAL*16 bytes)
// slots[0..31] = logdet partials, slots[63] = wave-completion counter (uint bits)

#if __has_builtin(__builtin_amdgcn_exp2f)
__device__ __forceinline__ float ex2(float x) { return __builtin_amdgcn_exp2f(x); }
#else
__device__ __forceinline__ float ex2(float x) { return __expf(0.6931471805599453f * x); }
#endif
#if __has_builtin(__builtin_amdgcn_rcpf)
__device__ __forceinline__ float frcp(float x) { return __builtin_amdgcn_rcpf(x); }
#else
__device__ __forceinline__ float frcp(float x) { return __fdividef(1.0f, x); }
#endif

#define LOG2E 1.4426950408889634f
#define C6 (6.0f * LOG2E)          // softmax temperature 2*B = 6, folded into exp2
#define CT (2.0f * LOG2E)          // tanh: e^{2a} = 2^{CT*a}

__device__ __forceinline__ float fast_tanh(float a) {
    const float e = ex2(CT * a);
    return fmaf(-2.0f, frcp(e + 1.0f), 1.0f);
}

__device__ __forceinline__ float softplus1(float v) {
    return fmaxf(v, 0.0f) + __logf(1.0f + ex2(-LOG2E * fabsf(v)));
}

// one (row, dim) rational-quadratic spline task; reads 32 f16 (4 swizzled chunks) from its
// LDS row, writes z, adds logdet. rowp = row base, cb = logical chunk base (4*slot), rot = lane rotation.
__device__ __forceinline__ void spline_task(
    const _Float16* __restrict__ rowp, int cb, int rot, float ud, int g, int d,
    float* __restrict__ out, float& ldacc)
{
    float vals[32];
    #pragma unroll
    for (int blk = 0; blk < 4; ++blk) {
        const v8h p = *(const v8h*)&rowp[((cb + blk + rot) & 15) * 8];   // 16-B aligned ds_read_b128
        #pragma unroll
        for (int j = 0; j < 8; ++j) vals[8 * blk + j] = (float)p[j];
    }
    // vals[0..9]=aw logits, [10..19]=ah logits, [20..28]=ad raw

    float mw = vals[0];
    #pragma unroll
    for (int i = 1; i < KK; ++i) mw = fmaxf(mw, vals[i]);
    const float mw8 = mw * C6;
    float sw = 0.0f;
    #pragma unroll
    for (int i = 0; i < KK; ++i) { vals[i] = ex2(fmaf(vals[i], C6, -mw8)); sw += vals[i]; }
    const float invw = frcp(sw);

    float mh = vals[10];
    #pragma unroll
    for (int i = 1; i < KK; ++i) mh = fmaxf(mh, vals[10 + i]);
    const float mh8 = mh * C6;
    float sh = 0.0f;
    #pragma unroll
    for (int i = 0; i < KK; ++i) { vals[10 + i] = ex2(fmaf(vals[10 + i], C6, -mh8)); sh += vals[10 + i]; }
    const float invh = frcp(sh);

    const float uc = fminf(fmaxf(ud, -BB), BB);
    const bool inside = (ud > -BB) && (ud < BB);

    // streaming bin search over RAW derivative values (sentinel: softplus(SENT)==1)
    float cw = 0.0f, ch = 0.0f;
    float xprev = -BB, yprev = -BB, rprev = SENT;
    float xk = -BB, yk = -BB, wk = 1.0f, hk2 = 1.0f, rdk = SENT, rdk1 = SENT;
    #pragma unroll
    for (int i = 0; i < KK; ++i) {
        cw += vals[i] * invw;
        ch += vals[10 + i] * invh;
        const float xnext = fmaf(6.0f, cw, -BB);
        const float ynext = fmaf(6.0f, ch, -BB);
        const float rnext = (i == KK - 1) ? SENT : vals[20 + i];
        const bool c = (i == 0) || (uc >= xprev);
        if (c) { xk = xprev; yk = yprev; wk = xnext - xprev; hk2 = ynext - yprev; rdk = rprev; rdk1 = rnext; }
        xprev = xnext; yprev = ynext; rprev = rnext;
    }
    const float dk = softplus1(rdk);
    const float dk1 = softplus1(rdk1);

    const float rwk = frcp(wk);
    const float sk = hk2 * rwk;
    const float xi = (uc - xk) * rwk;
    const float om = 1.0f - xi;
    const float denom = sk + (dk1 + dk - 2.0f * sk) * xi * om;
    const float rden = frcp(denom);
    const float ynum = sk * xi * xi + dk * xi * om;
    const float yv = yk + hk2 * ynum * rden;
    const float larg = dk1 * xi * xi + 2.0f * sk * xi * om + dk * om * om;
    const float ldet = __logf(sk * sk * larg * rden * rden);

    out[g * 16 + 8 + d] = inside ? yv : ud;
    ldacc += inside ? ldet : 0.0f;
}

// ---- prep: pack B-fragments with bias folded into k=8/k=50 row; zero logdet slots + counter ----
__global__ __launch_bounds__(256) void nsf_prep(
    const float* __restrict__ w0, const float* __restrict__ b0,
    const float* __restrict__ w1, const float* __restrict__ b1,
    const float* __restrict__ ww, const float* __restrict__ bw,
    const float* __restrict__ wh, const float* __restrict__ bh,
    const float* __restrict__ wd, const float* __restrict__ bd,
    v8h* __restrict__ wsv, float* __restrict__ wsf)
{
    const int t = blockIdx.x * 256 + threadIdx.x;
    if (t < 64) wsf[SLOTS_OFF + t] = 0.0f;
    if (t >= FRAG_TOTAL) return;

    v8h v;
    #pragma unroll
    for (int j = 0; j < 8; ++j) v[j] = (_Float16)0.0f;

    if (t < W1_OFF) {                       // W0: 9x50 (row 8 = b0) padded to K=32, 4 col tiles
        const int tile = t >> 6, lane = t & 63, q = lane >> 4, n = tile * 16 + (lane & 15);
        if (n < 50) {
            #pragma unroll
            for (int j = 0; j < 8; ++j) {
                const int k = q * 8 + j;
                if (k < 8)       v[j] = (_Float16)w0[k * 50 + n];
                else if (k == 8) v[j] = (_Float16)b0[n];
            }
        }
    } else if (t < WC_OFF) {                // W1: 51x50 (row 50 = b1), 2 k-steps, 4 col tiles
        int p = t - W1_OFF;
        const int step = p >> 8; p &= 255;
        const int tile = p >> 6, lane = p & 63, q = lane >> 4, n = tile * 16 + (lane & 15);
        if (n < 50) {
            #pragma unroll
            for (int j = 0; j < 8; ++j) {
                const int k = step * 32 + q * 8 + j;
                if (k < 50)       v[j] = (_Float16)w1[k * 50 + n];
                else if (k == 50) v[j] = (_Float16)b1[n];
            }
        }
    } else {                                // WC: 51x256 (row 50 = bias), cols c' = d*32 + jj
        int p = t - WC_OFF;
        const int step = p >> 10; p &= 1023;
        const int tile = p >> 6, lane = p & 63, q = lane >> 4;
        const int cp = tile * 16 + (lane & 15);
        const int d = cp >> 5, jj = cp & 31;
        #pragma unroll
        for (int j = 0; j < 8; ++j) {
            const int k = step * 32 + q * 8 + j;
            float val = 0.0f;
            if (k < 50) {
                if (jj < 10)      val = ww[k * 80 + d * 10 + jj];
                else if (jj < 20) val = wh[k * 80 + d * 10 + (jj - 10)];
                else if (jj < 29) val = wd[k * 72 + d * 9 + (jj - 20)];
            } else if (k == 50) {
                if (jj < 10)      val = bw[d * 10 + jj];
                else if (jj < 20) val = bh[d * 10 + (jj - 10)];
                else if (jj < 29) val = bd[d * 9 + (jj - 20)];
            }
            v[j] = (_Float16)val;
        }
    }
    wsv[t] = v;
}

// ---- main v6: 128 threads = 2 independent waves (each: 2 tiles, private segments, no sync).
//      LDS 17408 B -> 9 blocks * 2 = 18 waves/CU capacity (vs ~10 at r5).
//      Chunk-rotation swizzle: physical 16-B chunk = (logical + l15 + (l15>>3)) & mask, same
//      on write & read. Hand-enumerated: all b64 writes / b128 reads land at the even
//      bank-distribution floor (<=2-way aliasing = free). Fixes r5's 3.1M conflicts.
//      finish merged via completion counter (r1-r3-validated) -> 2 dispatches/iteration.
__global__ __launch_bounds__(128) void nsf_main_v6(
    const float* __restrict__ x,
    const v8h* __restrict__ wsv,
    float* __restrict__ out, float* __restrict__ slots)
{
    __shared__ __align__(16) _Float16 smem[4 * SEGF16];   // 17408 B
    const int w = threadIdx.x >> 6;
    const int lane = threadIdx.x & 63;
    const int q = lane >> 4, l15 = lane & 15;
    const int rot = l15 + (l15 >> 3);                     // bank-spread rotation (injects l15 bit3)
    _Float16* segA = &smem[(2 * w) * SEGF16];
    _Float16* segB = &smem[(2 * w + 1) * SEGF16];
    const int waveId = blockIdx.x * 2 + w;
    const int R0 = waveId * 32;                           // tile A: R0.., tile B: R0+16..

    const float4* xv = (const float4*)x;
    float4* ov = (float4*)out;

    // prefetch epilogue u values (4 tasks)
    const float uA0 = x[(R0 + l15) * 16 + 8 + q];
    const float uA1 = x[(R0 + l15) * 16 + 12 + q];
    const float uB0 = x[(R0 + 16 + l15) * 16 + 8 + q];
    const float uB1 = x[(R0 + 16 + l15) * 16 + 12 + q];

    // passthrough of the 8 scale dims: 64 lanes cover this wave's 32 rows x 2 float4
    {
        const int gg = R0 + (lane >> 1);
        const int part = lane & 1;
        ov[gg * 4 + part] = xv[gg * 4 + part];
    }

    // ---- phase 0: zd fragments for both tiles (k<8 real, k=8 -> 1.0 bias row) ----
    v8h aA, aB;
    #pragma unroll
    for (int j = 0; j < 8; ++j) { aA[j] = (_Float16)0.0f; aB[j] = (_Float16)0.0f; }
    if (lane < 16) {
        const float4 f0 = xv[(R0 + lane) * 4 + 0];
        const float4 f1 = xv[(R0 + lane) * 4 + 1];
        aA[0] = (_Float16)f0.x; aA[1] = (_Float16)f0.y; aA[2] = (_Float16)f0.z; aA[3] = (_Float16)f0.w;
        aA[4] = (_Float16)f1.x; aA[5] = (_Float16)f1.y; aA[6] = (_Float16)f1.z; aA[7] = (_Float16)f1.w;
        const float4 g0 = xv[(R0 + 16 + lane) * 4 + 0];
        const float4 g1 = xv[(R0 + 16 + lane) * 4 + 1];
        aB[0] = (_Float16)g0.x; aB[1] = (_Float16)g0.y; aB[2] = (_Float16)g0.z; aB[3] = (_Float16)g0.w;
        aB[4] = (_Float16)g1.x; aB[5] = (_Float16)g1.y; aB[6] = (_Float16)g1.z; aB[7] = (_Float16)g1.w;
    }
    if (q == 1) { aA[0] = (_Float16)1.0f; aB[0] = (_Float16)1.0f; }   // k=8: bias row

    // ---- phase 1: h1 = tanh(zd @ [w0;b0]) -> swizzled rows, stride HS=80 ----
    // swapped mfma: lane (l15=m,q) holds n = t*16+q*4+rg -> one packed b64 write
    #pragma unroll
    for (int t = 0; t < 4; ++t) {
        const v8h b = wsv[W0_OFF + t * 64 + lane];
        v4f cA = __builtin_amdgcn_mfma_f32_16x16x32_f16(b, aA, (v4f)(0.0f), 0, 0, 0);
        v4f cB = __builtin_amdgcn_mfma_f32_16x16x32_f16(b, aB, (v4f)(0.0f), 0, 0, 0);
        v4h pA, pB;
        #pragma unroll
        for (int rg = 0; rg < 4; ++rg) {
            pA[rg] = (_Float16)fast_tanh(cA[rg]);
            pB[rg] = (_Float16)fast_tanh(cB[rg]);
        }
        const int pc = ((2 * t + (q >> 1)) + rot) & 7;     // logical chunk 2t+(q>>1), swizzled
        const int o = l15 * HS + pc * 8 + (q & 1) * 4;
        *(v4h*)&segA[o] = pA;
        *(v4h*)&segB[o] = pB;
    }

    // ---- phase 2: h2 = tanh(h1 @ [w1;b1]) (reads then overwrites same chunks, in-order) ----
    v8h A0A, A1A, A0B, A1B;
    {
        const int p0 = ((q + rot) & 7) * 8;                // logical chunk q   (k = q*8..)
        const int p1 = ((q + 4 + rot) & 7) * 8;            // logical chunk q+4 (k = 32+q*8..)
        A0A = *(const v8h*)&segA[l15 * HS + p0];
        A1A = *(const v8h*)&segA[l15 * HS + p1];
        A0B = *(const v8h*)&segB[l15 * HS + p0];
        A1B = *(const v8h*)&segB[l15 * HS + p1];
    }
    if (q == 2) { A1A[2] = (_Float16)1.0f; A1B[2] = (_Float16)1.0f; }   // k=50: bias row
    #pragma unroll
    for (int t = 0; t < 4; ++t) {
        const v8h bf0 = wsv[W1_OFF + t * 64 + lane];
        const v8h bf1 = wsv[W1_OFF + 256 + t * 64 + lane];
        v4f cA = __builtin_amdgcn_mfma_f32_16x16x32_f16(bf0, A0A, (v4f)(0.0f), 0, 0, 0);
        cA = __builtin_amdgcn_mfma_f32_16x16x32_f16(bf1, A1A, cA, 0, 0, 0);
        v4f cB = __builtin_amdgcn_mfma_f32_16x16x32_f16(bf0, A0B, (v4f)(0.0f), 0, 0, 0);
        cB = __builtin_amdgcn_mfma_f32_16x16x32_f16(bf1, A1B, cB, 0, 0, 0);
        v4h pA, pB;
        #pragma unroll
        for (int rg = 0; rg < 4; ++rg) {
            pA[rg] = (_Float16)fast_tanh(cA[rg]);
            pB[rg] = (_Float16)fast_tanh(cB[rg]);
        }
        const int pc = ((2 * t + (q >> 1)) + rot) & 7;
        const int o = l15 * HS + pc * 8 + (q & 1) * 4;
        *(v4h*)&segA[o] = pA;
        *(v4h*)&segB[o] = pB;
    }

    // ---- phase 3 h2-frags (reload) ----
    {
        const int p0 = ((q + rot) & 7) * 8;
        const int p1 = ((q + 4 + rot) & 7) * 8;
        A0A = *(const v8h*)&segA[l15 * HS + p0];
        A1A = *(const v8h*)&segA[l15 * HS + p1];
        A0B = *(const v8h*)&segB[l15 * HS + p0];
        A1B = *(const v8h*)&segB[l15 * HS + p1];
    }
    if (q == 2) { A1A[2] = (_Float16)1.0f; A1B[2] = (_Float16)1.0f; }   // k=50: bias row

    float ldacc = 0.0f;

    // ---- phase 3 first half: dims 0-3 (t = 0..7) -> 16 swizzled chunks, stride SROW=136 ----
    #pragma unroll 2
    for (int t = 0; t < 8; ++t) {
        const v8h bf0 = wsv[WC_OFF + t * 64 + lane];
        const v8h bf1 = wsv[WC_OFF + 1024 + t * 64 + lane];
        v4f cA = __builtin_amdgcn_mfma_f32_16x16x32_f16(bf0, A0A, (v4f)(0.0f), 0, 0, 0);
        cA = __builtin_amdgcn_mfma_f32_16x16x32_f16(bf1, A1A, cA, 0, 0, 0);
        v4f cB = __builtin_amdgcn_mfma_f32_16x16x32_f16(bf0, A0B, (v4f)(0.0f), 0, 0, 0);
        cB = __builtin_amdgcn_mfma_f32_16x16x32_f16(bf1, A1B, cB, 0, 0, 0);
        v4h pA, pB;
        #pragma unroll
        for (int rg = 0; rg < 4; ++rg) { pA[rg] = (_Float16)cA[rg]; pB[rg] = (_Float16)cB[rg]; }
        const int pc = ((2 * t + (q >> 1)) + rot) & 15;
        const int o = l15 * SROW + pc * 8 + (q & 1) * 4;
        *(v4h*)&segA[o] = pA;
        *(v4h*)&segB[o] = pB;
    }

    // ---- epilogue tasks tt=0 (d = q): in-order DS reads precede second-half overwrites ----
    spline_task(&segA[l15 * SROW], q * 4, rot, uA0, R0 + l15, q, out, ldacc);
    spline_task(&segB[l15 * SROW], q * 4, rot, uB0, R0 + 16 + l15, q, out, ldacc);

    // ---- phase 3 second half: dims 4-7 (t = 8..15) -> SAME chunks (buffer reuse) ----
    #pragma unroll 2
    for (int t = 8; t < 16; ++t) {
        const v8h bf0 = wsv[WC_OFF + t * 64 + lane];
        const v8h bf1 = wsv[WC_OFF + 1024 + t * 64 + lane];
        v4f cA = __builtin_amdgcn_mfma_f32_16x16x32_f16(bf0, A0A, (v4f)(0.0f), 0, 0, 0);
        cA = __builtin_amdgcn_mfma_f32_16x16x32_f16(bf1, A1A, cA, 0, 0, 0);
        v4f cB = __builtin_amdgcn_mfma_f32_16x16x32_f16(bf0, A0B, (v4f)(0.0f), 0, 0, 0);
        cB = __builtin_amdgcn_mfma_f32_16x16x32_f16(bf1, A1B, cB, 0, 0, 0);
        v4h pA, pB;
        #pragma unroll
        for (int rg = 0; rg < 4; ++rg) { pA[rg] = (_Float16)cA[rg]; pB[rg] = (_Float16)cB[rg]; }
        const int pc = ((2 * (t - 8) + (q >> 1)) + rot) & 15;
        const int o = l15 * SROW + pc * 8 + (q & 1) * 4;
        *(v4h*)&segA[o] = pA;
        *(v4h*)&segB[o] = pB;
    }

    // ---- epilogue tasks tt=1 (d = q+4, same slots) ----
    spline_task(&segA[l15 * SROW], q * 4, rot, uA1, R0 + l15, q + 4, out, ldacc);
    spline_task(&segB[l15 * SROW], q * 4, rot, uB1, R0 + 16 + l15, q + 4, out, ldacc);

    // ---- logdet: wave shuffle-reduce -> slot-spread atomics; last wave finalizes ----
    #pragma unroll
    for (int off = 32; off > 0; off >>= 1) ldacc += __shfl_down(ldacc, off);
    int last = 0;
    if (lane == 0) {
        atomicAdd(&slots[waveId & 31], ldacc);
        __threadfence();
        const unsigned old = atomicAdd((unsigned int*)&slots[63], 1u);
        last = (old == (unsigned)(W_TOTAL - 1)) ? 1 : 0;
    }
    last = __shfl(last, 0);
    if (last) {
        float v = (lane < 32) ? atomicAdd(&slots[lane], 0.0f) : 0.0f;
        #pragma unroll
        for (int off = 32; off > 0; off >>= 1) v += __shfl_down(v, off);
        if (lane == 0) out[(size_t)NROWS * 16] = v;
    }
}

extern "C" void kernel_launch(void* const* d_in, const int* in_sizes, int n_in,
                              void* d_out, int out_size, void* d_ws, size_t ws_size,
                              hipStream_t stream) {
    const float* x  = (const float*)d_in[0];
    const float* w0 = (const float*)d_in[1];
    const float* b0 = (const float*)d_in[2];
    const float* w1 = (const float*)d_in[3];
    const float* b1 = (const float*)d_in[4];
    const float* ww = (const float*)d_in[5];
    const float* bw = (const float*)d_in[6];
    const float* wh = (const float*)d_in[7];
    const float* bh = (const float*)d_in[8];
    const float* wd = (const float*)d_in[9];
    const float* bd = (const float*)d_in[10];

    float* out = (float*)d_out;
    v8h* wsv = (v8h*)d_ws;                   // 45 KB packed B-fragments (bias folded)
    float* wsf = (float*)d_ws;               // f32 view for slots
    float* slots = wsf + SLOTS_OFF;

    hipLaunchKernelGGL(nsf_prep, dim3((FRAG_TOTAL + 255) / 256), dim3(256), 0, stream,
                       w0, b0, w1, b1, ww, bw, wh, bh, wd, bd, wsv, wsf);
    hipLaunchKernelGGL(nsf_main_v6, dim3(NROWS / 64), dim3(128), 0, stream,
                       x, wsv, out, slots);
}

// Round 7
// 156.578 us; speedup vs baseline: 2.0822x; 2.0822x over previous
//
#include <hip/hip_runtime.h>

#define NROWS 262144
#define KK 10
#define BB 3.0f
#define SROW 132                   // phase-3 row stride in f16: 264 B = 66 dw == 2 mod 4 -> full bank spread
#define HS 84                      // phase-1/2 h row stride in f16: 168 B = 42 dw == 2 mod 4 -> full bank spread
#define SEGF16 (16 * SROW)         // 2112 f16 = 4224 B per tile segment
#define SENT 0.54132485f           // ln(e-1): softplus(SENT) == 1.0 (boundary derivative)

typedef _Float16 v8h __attribute__((ext_vector_type(8)));
typedef _Float16 v4h __attribute__((ext_vector_type(4)));
typedef float v4f __attribute__((ext_vector_type(4)));

// d_ws layout: v8h frags: W0[4*64] | W1[2*4*64] | WC[2*16*64] ; then f32 slots[64]
#define W0_OFF 0
#define W1_OFF 256
#define WC_OFF 768
#define FRAG_TOTAL 2816
#define SLOTS_OFF (FRAG_TOTAL * 4)   // f32 units from ws base (FRAG_TOTAL*16 bytes)

#if __has_builtin(__builtin_amdgcn_exp2f)
__device__ __forceinline__ float ex2(float x) { return __builtin_amdgcn_exp2f(x); }
#else
__device__ __forceinline__ float ex2(float x) { return __expf(0.6931471805599453f * x); }
#endif
#if __has_builtin(__builtin_amdgcn_rcpf)
__device__ __forceinline__ float frcp(float x) { return __builtin_amdgcn_rcpf(x); }
#else
__device__ __forceinline__ float frcp(float x) { return __fdividef(1.0f, x); }
#endif

#define LOG2E 1.4426950408889634f
#define C6 (6.0f * LOG2E)          // softmax temperature 2*B = 6, folded into exp2
#define CT (2.0f * LOG2E)          // tanh: e^{2a} = 2^{CT*a}

__device__ __forceinline__ float fast_tanh(float a) {
    const float e = ex2(CT * a);
    return fmaf(-2.0f, frcp(e + 1.0f), 1.0f);
}

__device__ __forceinline__ float softplus1(float v) {
    return fmaxf(v, 0.0f) + __logf(1.0f + ex2(-LOG2E * fabsf(v)));
}

// one (row, dim) rational-quadratic spline task; reads 32 f16 via 8 conflict-free b64 loads,
// writes z, adds logdet
__device__ __forceinline__ void spline_task(
    const _Float16* __restrict__ sg, int base, float ud, int g, int d,
    float* __restrict__ out, float& ldacc)
{
    float vals[32];
    #pragma unroll
    for (int blk = 0; blk < 8; ++blk) {
        const v4h p = *(const v4h*)&sg[base + blk * 4];   // 8-B aligned ds_read_b64
        vals[4 * blk + 0] = (float)p[0];
        vals[4 * blk + 1] = (float)p[1];
        vals[4 * blk + 2] = (float)p[2];
        vals[4 * blk + 3] = (float)p[3];
    }
    // vals[0..9]=aw logits, [10..19]=ah logits, [20..28]=ad raw

    float mw = vals[0];
    #pragma unroll
    for (int i = 1; i < KK; ++i) mw = fmaxf(mw, vals[i]);
    const float mw8 = mw * C6;
    float sw = 0.0f;
    #pragma unroll
    for (int i = 0; i < KK; ++i) { vals[i] = ex2(fmaf(vals[i], C6, -mw8)); sw += vals[i]; }
    const float invw = frcp(sw);

    float mh = vals[10];
    #pragma unroll
    for (int i = 1; i < KK; ++i) mh = fmaxf(mh, vals[10 + i]);
    const float mh8 = mh * C6;
    float sh = 0.0f;
    #pragma unroll
    for (int i = 0; i < KK; ++i) { vals[10 + i] = ex2(fmaf(vals[10 + i], C6, -mh8)); sh += vals[10 + i]; }
    const float invh = frcp(sh);

    const float uc = fminf(fmaxf(ud, -BB), BB);
    const bool inside = (ud > -BB) && (ud < BB);

    // streaming bin search over RAW derivative values (sentinel: softplus(SENT)==1)
    float cw = 0.0f, ch = 0.0f;
    float xprev = -BB, yprev = -BB, rprev = SENT;
    float xk = -BB, yk = -BB, wk = 1.0f, hk2 = 1.0f, rdk = SENT, rdk1 = SENT;
    #pragma unroll
    for (int i = 0; i < KK; ++i) {
        cw += vals[i] * invw;
        ch += vals[10 + i] * invh;
        const float xnext = fmaf(6.0f, cw, -BB);
        const float ynext = fmaf(6.0f, ch, -BB);
        const float rnext = (i == KK - 1) ? SENT : vals[20 + i];
        const bool c = (i == 0) || (uc >= xprev);
        if (c) { xk = xprev; yk = yprev; wk = xnext - xprev; hk2 = ynext - yprev; rdk = rprev; rdk1 = rnext; }
        xprev = xnext; yprev = ynext; rprev = rnext;
    }
    const float dk = softplus1(rdk);
    const float dk1 = softplus1(rdk1);

    const float rwk = frcp(wk);
    const float sk = hk2 * rwk;
    const float xi = (uc - xk) * rwk;
    const float om = 1.0f - xi;
    const float denom = sk + (dk1 + dk - 2.0f * sk) * xi * om;
    const float rden = frcp(denom);
    const float ynum = sk * xi * xi + dk * xi * om;
    const float yv = yk + hk2 * ynum * rden;
    const float larg = dk1 * xi * xi + 2.0f * sk * xi * om + dk * om * om;
    const float ldet = __logf(sk * sk * larg * rden * rden);

    out[g * 16 + 8 + d] = inside ? yv : ud;
    ldacc += inside ? ldet : 0.0f;
}

// ---- prep: pack B-fragments with bias folded into k=8/k=50 row; zero logdet slots ----
__global__ __launch_bounds__(256) void nsf_prep(
    const float* __restrict__ w0, const float* __restrict__ b0,
    const float* __restrict__ w1, const float* __restrict__ b1,
    const float* __restrict__ ww, const float* __restrict__ bw,
    const float* __restrict__ wh, const float* __restrict__ bh,
    const float* __restrict__ wd, const float* __restrict__ bd,
    v8h* __restrict__ wsv, float* __restrict__ wsf)
{
    const int t = blockIdx.x * 256 + threadIdx.x;
    if (t < 64) wsf[SLOTS_OFF + t] = 0.0f;
    if (t >= FRAG_TOTAL) return;

    v8h v;
    #pragma unroll
    for (int j = 0; j < 8; ++j) v[j] = (_Float16)0.0f;

    if (t < W1_OFF) {                       // W0: 9x50 (row 8 = b0) padded to K=32, 4 col tiles
        const int tile = t >> 6, lane = t & 63, q = lane >> 4, n = tile * 16 + (lane & 15);
        if (n < 50) {
            #pragma unroll
            for (int j = 0; j < 8; ++j) {
                const int k = q * 8 + j;
                if (k < 8)       v[j] = (_Float16)w0[k * 50 + n];
                else if (k == 8) v[j] = (_Float16)b0[n];
            }
        }
    } else if (t < WC_OFF) {                // W1: 51x50 (row 50 = b1), 2 k-steps, 4 col tiles
        int p = t - W1_OFF;
        const int step = p >> 8; p &= 255;
        const int tile = p >> 6, lane = p & 63, q = lane >> 4, n = tile * 16 + (lane & 15);
        if (n < 50) {
            #pragma unroll
            for (int j = 0; j < 8; ++j) {
                const int k = step * 32 + q * 8 + j;
                if (k < 50)       v[j] = (_Float16)w1[k * 50 + n];
                else if (k == 50) v[j] = (_Float16)b1[n];
            }
        }
    } else {                                // WC: 51x256 (row 50 = bias), cols c' = d*32 + jj
        int p = t - WC_OFF;
        const int step = p >> 10; p &= 1023;
        const int tile = p >> 6, lane = p & 63, q = lane >> 4;
        const int cp = tile * 16 + (lane & 15);
        const int d = cp >> 5, jj = cp & 31;
        #pragma unroll
        for (int j = 0; j < 8; ++j) {
            const int k = step * 32 + q * 8 + j;
            float val = 0.0f;
            if (k < 50) {
                if (jj < 10)      val = ww[k * 80 + d * 10 + jj];
                else if (jj < 20) val = wh[k * 80 + d * 10 + (jj - 10)];
                else if (jj < 29) val = wd[k * 72 + d * 9 + (jj - 20)];
            } else if (k == 50) {
                if (jj < 10)      val = bw[d * 10 + jj];
                else if (jj < 20) val = bh[d * 10 + (jj - 10)];
                else if (jj < 29) val = bd[d * 9 + (jj - 20)];
            }
            v[j] = (_Float16)val;
        }
    }
    wsv[t] = v;
}

// ---- main v7: r5 structure (swapped MFMA -> packed b64 LDS writes; 64-thread blocks;
//      separate finish kernel, NO grid fence - r6 lesson: per-wave __threadfence +
//      same-address atomics cost ~180 us), with CONFLICT-FREE LDS strides:
//      all rows at dword-stride == 2 mod 4 (SROW 264 B, HS 168 B), all DS ops b64.
//      r4 empirically proved the 264-B stride is conflict-free (262K counter);
//      r5's 16-B-aligned strides (for b128) reintroduced 4-way aliasing (3.1M).
__global__ __launch_bounds__(64, 2) void nsf_main_v7(
    const float* __restrict__ x,
    const v8h* __restrict__ wsv,
    float* __restrict__ out, float* __restrict__ slots)
{
    __shared__ __align__(16) _Float16 smem[2 * SEGF16];   // 8448 B
    const int lane = threadIdx.x & 63;
    const int q = lane >> 4, l15 = lane & 15;
    _Float16* segA = &smem[0];
    _Float16* segB = &smem[SEGF16];
    const int R0 = blockIdx.x * 32;                       // tile A: R0.., tile B: R0+16..

    const float4* xv = (const float4*)x;
    float4* ov = (float4*)out;

    // prefetch epilogue u values (4 tasks)
    const float uA0 = x[(R0 + l15) * 16 + 8 + q];
    const float uA1 = x[(R0 + l15) * 16 + 12 + q];
    const float uB0 = x[(R0 + 16 + l15) * 16 + 8 + q];
    const float uB1 = x[(R0 + 16 + l15) * 16 + 12 + q];

    // passthrough of the 8 scale dims: all 64 lanes cover 32 rows x 2 float4
    {
        const int gg = R0 + (lane >> 1);
        const int part = lane & 1;
        ov[gg * 4 + part] = xv[gg * 4 + part];
    }

    // ---- phase 0: zd fragments for both tiles (k<8 real, k=8 -> 1.0 bias row) ----
    v8h aA, aB;
    #pragma unroll
    for (int j = 0; j < 8; ++j) { aA[j] = (_Float16)0.0f; aB[j] = (_Float16)0.0f; }
    if (lane < 16) {
        const float4 f0 = xv[(R0 + lane) * 4 + 0];
        const float4 f1 = xv[(R0 + lane) * 4 + 1];
        aA[0] = (_Float16)f0.x; aA[1] = (_Float16)f0.y; aA[2] = (_Float16)f0.z; aA[3] = (_Float16)f0.w;
        aA[4] = (_Float16)f1.x; aA[5] = (_Float16)f1.y; aA[6] = (_Float16)f1.z; aA[7] = (_Float16)f1.w;
        const float4 g0 = xv[(R0 + 16 + lane) * 4 + 0];
        const float4 g1 = xv[(R0 + 16 + lane) * 4 + 1];
        aB[0] = (_Float16)g0.x; aB[1] = (_Float16)g0.y; aB[2] = (_Float16)g0.z; aB[3] = (_Float16)g0.w;
        aB[4] = (_Float16)g1.x; aB[5] = (_Float16)g1.y; aB[6] = (_Float16)g1.z; aB[7] = (_Float16)g1.w;
    }
    if (q == 1) { aA[0] = (_Float16)1.0f; aB[0] = (_Float16)1.0f; }   // k=8: bias row

    // ---- phase 1: h1 = tanh(zd @ [w0;b0]) -> rows stride HS=84 ----
    // swapped mfma: lane (l15=m,q) holds n = t*16+q*4+rg -> one packed b64 write
    #pragma unroll
    for (int t = 0; t < 4; ++t) {
        const v8h b = wsv[W0_OFF + t * 64 + lane];
        v4f cA = __builtin_amdgcn_mfma_f32_16x16x32_f16(b, aA, (v4f)(0.0f), 0, 0, 0);
        v4f cB = __builtin_amdgcn_mfma_f32_16x16x32_f16(b, aB, (v4f)(0.0f), 0, 0, 0);
        v4h pA, pB;
        #pragma unroll
        for (int rg = 0; rg < 4; ++rg) {
            pA[rg] = (_Float16)fast_tanh(cA[rg]);
            pB[rg] = (_Float16)fast_tanh(cB[rg]);
        }
        const int o = l15 * HS + t * 16 + q * 4;   // byte = l15*168 + t*32 + q*8 (8-B aligned)
        *(v4h*)&segA[o] = pA;
        *(v4h*)&segB[o] = pB;
    }

    // ---- phase 2: h2 = tanh(h1 @ [w1;b1]) (reads then overwrites same region, in-order) ----
    // frag loads as b64 pairs (168-B rows are 8-B aligned, not 16)
    v8h A0A, A1A, A0B, A1B;
    {
        const int o0 = l15 * HS + q * 8;
        const int o1 = l15 * HS + 32 + q * 8;
        const v4h a0l = *(const v4h*)&segA[o0], a0h = *(const v4h*)&segA[o0 + 4];
        const v4h a1l = *(const v4h*)&segA[o1], a1h = *(const v4h*)&segA[o1 + 4];
        const v4h b0l = *(const v4h*)&segB[o0], b0h = *(const v4h*)&segB[o0 + 4];
        const v4h b1l = *(const v4h*)&segB[o1], b1h = *(const v4h*)&segB[o1 + 4];
        #pragma unroll
        for (int j = 0; j < 4; ++j) {
            A0A[j] = a0l[j]; A0A[4 + j] = a0h[j];
            A1A[j] = a1l[j]; A1A[4 + j] = a1h[j];
            A0B[j] = b0l[j]; A0B[4 + j] = b0h[j];
            A1B[j] = b1l[j]; A1B[4 + j] = b1h[j];
        }
    }
    if (q == 2) { A1A[2] = (_Float16)1.0f; A1B[2] = (_Float16)1.0f; }   // k=50: bias row
    #pragma unroll
    for (int t = 0; t < 4; ++t) {
        const v8h bf0 = wsv[W1_OFF + t * 64 + lane];
        const v8h bf1 = wsv[W1_OFF + 256 + t * 64 + lane];
        v4f cA = __builtin_amdgcn_mfma_f32_16x16x32_f16(bf0, A0A, (v4f)(0.0f), 0, 0, 0);
        cA = __builtin_amdgcn_mfma_f32_16x16x32_f16(bf1, A1A, cA, 0, 0, 0);
        v4f cB = __builtin_amdgcn_mfma_f32_16x16x32_f16(bf0, A0B, (v4f)(0.0f), 0, 0, 0);
        cB = __builtin_amdgcn_mfma_f32_16x16x32_f16(bf1, A1B, cB, 0, 0, 0);
        v4h pA, pB;
        #pragma unroll
        for (int rg = 0; rg < 4; ++rg) {
            pA[rg] = (_Float16)fast_tanh(cA[rg]);
            pB[rg] = (_Float16)fast_tanh(cB[rg]);
        }
        const int o = l15 * HS + t * 16 + q * 4;
        *(v4h*)&segA[o] = pA;
        *(v4h*)&segB[o] = pB;
    }

    // ---- phase 3 h2-frags (reload, b64 pairs) ----
    {
        const int o0 = l15 * HS + q * 8;
        const int o1 = l15 * HS + 32 + q * 8;
        const v4h a0l = *(const v4h*)&segA[o0], a0h = *(const v4h*)&segA[o0 + 4];
        const v4h a1l = *(const v4h*)&segA[o1], a1h = *(const v4h*)&segA[o1 + 4];
        const v4h b0l = *(const v4h*)&segB[o0], b0h = *(const v4h*)&segB[o0 + 4];
        const v4h b1l = *(const v4h*)&segB[o1], b1h = *(const v4h*)&segB[o1 + 4];
        #pragma unroll
        for (int j = 0; j < 4; ++j) {
            A0A[j] = a0l[j]; A0A[4 + j] = a0h[j];
            A1A[j] = a1l[j]; A1A[4 + j] = a1h[j];
            A0B[j] = b0l[j]; A0B[4 + j] = b0h[j];
            A1B[j] = b1l[j]; A1B[4 + j] = b1h[j];
        }
    }
    if (q == 2) { A1A[2] = (_Float16)1.0f; A1B[2] = (_Float16)1.0f; }   // k=50: bias row

    float ldacc = 0.0f;

    // ---- phase 3 first half: dims 0-3 (t = 0..7) -> slots 0..3, stride SROW=132 ----
    #pragma unroll 2
    for (int t = 0; t < 8; ++t) {
        const v8h bf0 = wsv[WC_OFF + t * 64 + lane];
        const v8h bf1 = wsv[WC_OFF + 1024 + t * 64 + lane];
        v4f cA = __builtin_amdgcn_mfma_f32_16x16x32_f16(bf0, A0A, (v4f)(0.0f), 0, 0, 0);
        cA = __builtin_amdgcn_mfma_f32_16x16x32_f16(bf1, A1A, cA, 0, 0, 0);
        v4f cB = __builtin_amdgcn_mfma_f32_16x16x32_f16(bf0, A0B, (v4f)(0.0f), 0, 0, 0);
        cB = __builtin_amdgcn_mfma_f32_16x16x32_f16(bf1, A1B, cB, 0, 0, 0);
        v4h pA, pB;
        #pragma unroll
        for (int rg = 0; rg < 4; ++rg) { pA[rg] = (_Float16)cA[rg]; pB[rg] = (_Float16)cB[rg]; }
        const int o = l15 * SROW + t * 16 + q * 4;   // byte = l15*264 + t*32 + q*8 (8-B aligned)
        *(v4h*)&segA[o] = pA;
        *(v4h*)&segB[o] = pB;
    }

    // ---- epilogue tasks tt=0 (d = q): in-order DS reads precede second-half overwrites ----
    spline_task(segA, l15 * SROW + q * 32, uA0, R0 + l15, q, out, ldacc);
    spline_task(segB, l15 * SROW + q * 32, uB0, R0 + 16 + l15, q, out, ldacc);

    // ---- phase 3 second half: dims 4-7 (t = 8..15) -> SAME slots 0..3 (buffer reuse) ----
    #pragma unroll 2
    for (int t = 8; t < 16; ++t) {
        const v8h bf0 = wsv[WC_OFF + t * 64 + lane];
        const v8h bf1 = wsv[WC_OFF + 1024 + t * 64 + lane];
        v4f cA = __builtin_amdgcn_mfma_f32_16x16x32_f16(bf0, A0A, (v4f)(0.0f), 0, 0, 0);
        cA = __builtin_amdgcn_mfma_f32_16x16x32_f16(bf1, A1A, cA, 0, 0, 0);
        v4f cB = __builtin_amdgcn_mfma_f32_16x16x32_f16(bf0, A0B, (v4f)(0.0f), 0, 0, 0);
        cB = __builtin_amdgcn_mfma_f32_16x16x32_f16(bf1, A1B, cB, 0, 0, 0);
        v4h pA, pB;
        #pragma unroll
        for (int rg = 0; rg < 4; ++rg) { pA[rg] = (_Float16)cA[rg]; pB[rg] = (_Float16)cB[rg]; }
        const int o = l15 * SROW + (t - 8) * 16 + q * 4;
        *(v4h*)&segA[o] = pA;
        *(v4h*)&segB[o] = pB;
    }

    // ---- epilogue tasks tt=1 (d = q+4, same slots) ----
    spline_task(segA, l15 * SROW + q * 32, uA1, R0 + l15, q + 4, out, ldacc);
    spline_task(segB, l15 * SROW + q * 32, uB1, R0 + 16 + l15, q + 4, out, ldacc);

    // ---- logdet: wave shuffle-reduce -> slot-spread atomics (64 slots) ----
    #pragma unroll
    for (int off = 32; off > 0; off >>= 1) ldacc += __shfl_down(ldacc, off);
    if (lane == 0) atomicAdd(&slots[blockIdx.x & 63], ldacc);
}

// ---- finish: sum the 64 partial slots into the scalar logdet output ----
__global__ void nsf_finish(const float* __restrict__ slots, float* __restrict__ ldp) {
    float v = slots[threadIdx.x];
    #pragma unroll
    for (int off = 32; off > 0; off >>= 1) v += __shfl_down(v, off);
    if (threadIdx.x == 0) *ldp = v;
}

extern "C" void kernel_launch(void* const* d_in, const int* in_sizes, int n_in,
                              void* d_out, int out_size, void* d_ws, size_t ws_size,
                              hipStream_t stream) {
    const float* x  = (const float*)d_in[0];
    const float* w0 = (const float*)d_in[1];
    const float* b0 = (const float*)d_in[2];
    const float* w1 = (const float*)d_in[3];
    const float* b1 = (const float*)d_in[4];
    const float* ww = (const float*)d_in[5];
    const float* bw = (const float*)d_in[6];
    const float* wh = (const float*)d_in[7];
    const float* bh = (const float*)d_in[8];
    const float* wd = (const float*)d_in[9];
    const float* bd = (const float*)d_in[10];

    float* out = (float*)d_out;
    float* ldp = out + (size_t)NROWS * 16;   // scalar logdet sum slot
    v8h* wsv = (v8h*)d_ws;                   // 45 KB packed B-fragments (bias folded)
    float* wsf = (float*)d_ws;               // f32 view for slots
    float* slots = wsf + SLOTS_OFF;

    hipLaunchKernelGGL(nsf_prep, dim3((FRAG_TOTAL + 255) / 256), dim3(256), 0, stream,
                       w0, b0, w1, b1, ww, bw, wh, bh, wd, bd, wsv, wsf);
    hipLaunchKernelGGL(nsf_main_v7, dim3(NROWS / 32), dim3(64), 0, stream,
                       x, wsv, out, slots);
    hipLaunchKernelGGL(nsf_finish, dim3(1), dim3(64), 0, stream, slots, ldp);
}

// Round 8
// 155.485 us; speedup vs baseline: 2.0968x; 1.0070x over previous
//
#include <hip/hip_runtime.h>

#define NROWS 262144
#define KK 10
#define BB 3.0f
#define SROW 132                   // phase-3 row stride in f16: 264 B = 66 dw == 2 mod 4 -> full bank spread
#define HS 84                      // phase-1/2 h row stride in f16: 168 B = 42 dw == 2 mod 4 -> full bank spread
#define SEGF16 (16 * SROW)         // 2112 f16 = 4224 B per tile segment
#define SENT 0.54132485f           // ln(e-1): softplus(SENT) == 1.0 (boundary derivative)

typedef _Float16 v8h __attribute__((ext_vector_type(8)));
typedef _Float16 v4h __attribute__((ext_vector_type(4)));
typedef float v4f __attribute__((ext_vector_type(4)));

// d_ws layout: v8h frags: W0[4*64] | W1[2*4*64] | WC[2*16*64] ; then f32 slots[64]
#define W0_OFF 0
#define W1_OFF 256
#define WC_OFF 768
#define FRAG_TOTAL 2816
#define SLOTS_OFF (FRAG_TOTAL * 4)   // f32 units from ws base (FRAG_TOTAL*16 bytes)

#if __has_builtin(__builtin_amdgcn_exp2f)
__device__ __forceinline__ float ex2(float x) { return __builtin_amdgcn_exp2f(x); }
#else
__device__ __forceinline__ float ex2(float x) { return __expf(0.6931471805599453f * x); }
#endif
#if __has_builtin(__builtin_amdgcn_rcpf)
__device__ __forceinline__ float frcp(float x) { return __builtin_amdgcn_rcpf(x); }
#else
__device__ __forceinline__ float frcp(float x) { return __fdividef(1.0f, x); }
#endif

#define LOG2E 1.4426950408889634f
#define C6 (6.0f * LOG2E)          // softmax temperature 2*B = 6, folded into exp2
#define CT (2.0f * LOG2E)          // tanh: e^{2a} = 2^{CT*a}

__device__ __forceinline__ float fast_tanh(float a) {
    const float e = ex2(CT * a);
    return fmaf(-2.0f, frcp(e + 1.0f), 1.0f);
}

__device__ __forceinline__ float softplus1(float v) {
    return fmaxf(v, 0.0f) + __logf(1.0f + ex2(-LOG2E * fabsf(v)));
}

// one (row, dim) rational-quadratic spline task; reads 32 f16 via 8 conflict-free b64 loads,
// writes z, adds logdet
__device__ __forceinline__ void spline_task(
    const _Float16* __restrict__ sg, int base, float ud, int g, int d,
    float* __restrict__ out, float& ldacc)
{
    float vals[32];
    #pragma unroll
    for (int blk = 0; blk < 8; ++blk) {
        const v4h p = *(const v4h*)&sg[base + blk * 4];   // 8-B aligned ds_read_b64
        vals[4 * blk + 0] = (float)p[0];
        vals[4 * blk + 1] = (float)p[1];
        vals[4 * blk + 2] = (float)p[2];
        vals[4 * blk + 3] = (float)p[3];
    }
    // vals[0..9]=aw logits, [10..19]=ah logits, [20..28]=ad raw

    float mw = vals[0];
    #pragma unroll
    for (int i = 1; i < KK; ++i) mw = fmaxf(mw, vals[i]);
    const float mw8 = mw * C6;
    float sw = 0.0f;
    #pragma unroll
    for (int i = 0; i < KK; ++i) { vals[i] = ex2(fmaf(vals[i], C6, -mw8)); sw += vals[i]; }
    const float invw = frcp(sw);

    float mh = vals[10];
    #pragma unroll
    for (int i = 1; i < KK; ++i) mh = fmaxf(mh, vals[10 + i]);
    const float mh8 = mh * C6;
    float sh = 0.0f;
    #pragma unroll
    for (int i = 0; i < KK; ++i) { vals[10 + i] = ex2(fmaf(vals[10 + i], C6, -mh8)); sh += vals[10 + i]; }
    const float invh = frcp(sh);

    const float uc = fminf(fmaxf(ud, -BB), BB);
    const bool inside = (ud > -BB) && (ud < BB);

    // streaming bin search over RAW derivative values (sentinel: softplus(SENT)==1)
    float cw = 0.0f, ch = 0.0f;
    float xprev = -BB, yprev = -BB, rprev = SENT;
    float xk = -BB, yk = -BB, wk = 1.0f, hk2 = 1.0f, rdk = SENT, rdk1 = SENT;
    #pragma unroll
    for (int i = 0; i < KK; ++i) {
        cw += vals[i] * invw;
        ch += vals[10 + i] * invh;
        const float xnext = fmaf(6.0f, cw, -BB);
        const float ynext = fmaf(6.0f, ch, -BB);
        const float rnext = (i == KK - 1) ? SENT : vals[20 + i];
        const bool c = (i == 0) || (uc >= xprev);
        if (c) { xk = xprev; yk = yprev; wk = xnext - xprev; hk2 = ynext - yprev; rdk = rprev; rdk1 = rnext; }
        xprev = xnext; yprev = ynext; rprev = rnext;
    }
    const float dk = softplus1(rdk);
    const float dk1 = softplus1(rdk1);

    const float rwk = frcp(wk);
    const float sk = hk2 * rwk;
    const float xi = (uc - xk) * rwk;
    const float om = 1.0f - xi;
    const float denom = sk + (dk1 + dk - 2.0f * sk) * xi * om;
    const float rden = frcp(denom);
    const float ynum = sk * xi * xi + dk * xi * om;
    const float yv = yk + hk2 * ynum * rden;
    const float larg = dk1 * xi * xi + 2.0f * sk * xi * om + dk * om * om;
    const float ldet = __logf(sk * sk * larg * rden * rden);

    out[g * 16 + 8 + d] = inside ? yv : ud;
    ldacc += inside ? ldet : 0.0f;
}

// ---- prep: pack B-fragments with bias folded into k=8/k=50 row; zero logdet slots ----
__global__ __launch_bounds__(256) void nsf_prep(
    const float* __restrict__ w0, const float* __restrict__ b0,
    const float* __restrict__ w1, const float* __restrict__ b1,
    const float* __restrict__ ww, const float* __restrict__ bw,
    const float* __restrict__ wh, const float* __restrict__ bh,
    const float* __restrict__ wd, const float* __restrict__ bd,
    v8h* __restrict__ wsv, float* __restrict__ wsf)
{
    const int t = blockIdx.x * 256 + threadIdx.x;
    if (t < 64) wsf[SLOTS_OFF + t] = 0.0f;
    if (t >= FRAG_TOTAL) return;

    v8h v;
    #pragma unroll
    for (int j = 0; j < 8; ++j) v[j] = (_Float16)0.0f;

    if (t < W1_OFF) {                       // W0: 9x50 (row 8 = b0) padded to K=32, 4 col tiles
        const int tile = t >> 6, lane = t & 63, q = lane >> 4, n = tile * 16 + (lane & 15);
        if (n < 50) {
            #pragma unroll
            for (int j = 0; j < 8; ++j) {
                const int k = q * 8 + j;
                if (k < 8)       v[j] = (_Float16)w0[k * 50 + n];
                else if (k == 8) v[j] = (_Float16)b0[n];
            }
        }
    } else if (t < WC_OFF) {                // W1: 51x50 (row 50 = b1), 2 k-steps, 4 col tiles
        int p = t - W1_OFF;
        const int step = p >> 8; p &= 255;
        const int tile = p >> 6, lane = p & 63, q = lane >> 4, n = tile * 16 + (lane & 15);
        if (n < 50) {
            #pragma unroll
            for (int j = 0; j < 8; ++j) {
                const int k = step * 32 + q * 8 + j;
                if (k < 50)       v[j] = (_Float16)w1[k * 50 + n];
                else if (k == 50) v[j] = (_Float16)b1[n];
            }
        }
    } else {                                // WC: 51x256 (row 50 = bias), cols c' = d*32 + jj
        int p = t - WC_OFF;
        const int step = p >> 10; p &= 1023;
        const int tile = p >> 6, lane = p & 63, q = lane >> 4;
        const int cp = tile * 16 + (lane & 15);
        const int d = cp >> 5, jj = cp & 31;
        #pragma unroll
        for (int j = 0; j < 8; ++j) {
            const int k = step * 32 + q * 8 + j;
            float val = 0.0f;
            if (k < 50) {
                if (jj < 10)      val = ww[k * 80 + d * 10 + jj];
                else if (jj < 20) val = wh[k * 80 + d * 10 + (jj - 10)];
                else if (jj < 29) val = wd[k * 72 + d * 9 + (jj - 20)];
            } else if (k == 50) {
                if (jj < 10)      val = bw[d * 10 + jj];
                else if (jj < 20) val = bh[d * 10 + (jj - 10)];
                else if (jj < 29) val = bd[d * 9 + (jj - 20)];
            }
            v[j] = (_Float16)val;
        }
    }
    wsv[t] = v;
}

// ---- main v8: v7 per-wave body (swapped MFMA -> b64 LDS writes, conflict-free strides,
//      NO fence — r6 lesson), but 128-thread blocks = 2 INDEPENDENT waves per workgroup
//      slot. Rationale: v7 is latency-bound at ~10 resident waves/CU with 1-wave blocks
//      (wg-slot-inefficient); 2-wave blocks double waves per slot -> up to 9 blocks x 2 =
//      18 waves/CU. r6 proved this shape compiles spill-free (VGPR 52 @ 17 KB LDS);
//      r6's regression was entirely the fence+counter tail, removed here.
__global__ __launch_bounds__(128) void nsf_main_v8(
    const float* __restrict__ x,
    const v8h* __restrict__ wsv,
    float* __restrict__ out, float* __restrict__ slots)
{
    __shared__ __align__(16) _Float16 smem[4 * SEGF16];   // 16896 B
    const int w = threadIdx.x >> 6;
    const int lane = threadIdx.x & 63;
    const int q = lane >> 4, l15 = lane & 15;
    _Float16* segA = &smem[(2 * w) * SEGF16];
    _Float16* segB = &smem[(2 * w + 1) * SEGF16];
    const int waveId = blockIdx.x * 2 + w;
    const int R0 = waveId * 32;                           // tile A: R0.., tile B: R0+16..

    const float4* xv = (const float4*)x;
    float4* ov = (float4*)out;

    // prefetch epilogue u values (4 tasks)
    const float uA0 = x[(R0 + l15) * 16 + 8 + q];
    const float uA1 = x[(R0 + l15) * 16 + 12 + q];
    const float uB0 = x[(R0 + 16 + l15) * 16 + 8 + q];
    const float uB1 = x[(R0 + 16 + l15) * 16 + 12 + q];

    // passthrough of the 8 scale dims: 64 lanes cover this wave's 32 rows x 2 float4
    {
        const int gg = R0 + (lane >> 1);
        const int part = lane & 1;
        ov[gg * 4 + part] = xv[gg * 4 + part];
    }

    // ---- phase 0: zd fragments for both tiles (k<8 real, k=8 -> 1.0 bias row) ----
    v8h aA, aB;
    #pragma unroll
    for (int j = 0; j < 8; ++j) { aA[j] = (_Float16)0.0f; aB[j] = (_Float16)0.0f; }
    if (lane < 16) {
        const float4 f0 = xv[(R0 + lane) * 4 + 0];
        const float4 f1 = xv[(R0 + lane) * 4 + 1];
        aA[0] = (_Float16)f0.x; aA[1] = (_Float16)f0.y; aA[2] = (_Float16)f0.z; aA[3] = (_Float16)f0.w;
        aA[4] = (_Float16)f1.x; aA[5] = (_Float16)f1.y; aA[6] = (_Float16)f1.z; aA[7] = (_Float16)f1.w;
        const float4 g0 = xv[(R0 + 16 + lane) * 4 + 0];
        const float4 g1 = xv[(R0 + 16 + lane) * 4 + 1];
        aB[0] = (_Float16)g0.x; aB[1] = (_Float16)g0.y; aB[2] = (_Float16)g0.z; aB[3] = (_Float16)g0.w;
        aB[4] = (_Float16)g1.x; aB[5] = (_Float16)g1.y; aB[6] = (_Float16)g1.z; aB[7] = (_Float16)g1.w;
    }
    if (q == 1) { aA[0] = (_Float16)1.0f; aB[0] = (_Float16)1.0f; }   // k=8: bias row

    // ---- phase 1: h1 = tanh(zd @ [w0;b0]) -> rows stride HS=84 ----
    // swapped mfma: lane (l15=m,q) holds n = t*16+q*4+rg -> one packed b64 write
    #pragma unroll
    for (int t = 0; t < 4; ++t) {
        const v8h b = wsv[W0_OFF + t * 64 + lane];
        v4f cA = __builtin_amdgcn_mfma_f32_16x16x32_f16(b, aA, (v4f)(0.0f), 0, 0, 0);
        v4f cB = __builtin_amdgcn_mfma_f32_16x16x32_f16(b, aB, (v4f)(0.0f), 0, 0, 0);
        v4h pA, pB;
        #pragma unroll
        for (int rg = 0; rg < 4; ++rg) {
            pA[rg] = (_Float16)fast_tanh(cA[rg]);
            pB[rg] = (_Float16)fast_tanh(cB[rg]);
        }
        const int o = l15 * HS + t * 16 + q * 4;   // byte = l15*168 + t*32 + q*8 (8-B aligned)
        *(v4h*)&segA[o] = pA;
        *(v4h*)&segB[o] = pB;
    }

    // ---- phase 2: h2 = tanh(h1 @ [w1;b1]) (reads then overwrites same region, in-order) ----
    // frag loads as b64 pairs (168-B rows are 8-B aligned, not 16)
    v8h A0A, A1A, A0B, A1B;
    {
        const int o0 = l15 * HS + q * 8;
        const int o1 = l15 * HS + 32 + q * 8;
        const v4h a0l = *(const v4h*)&segA[o0], a0h = *(const v4h*)&segA[o0 + 4];
        const v4h a1l = *(const v4h*)&segA[o1], a1h = *(const v4h*)&segA[o1 + 4];
        const v4h b0l = *(const v4h*)&segB[o0], b0h = *(const v4h*)&segB[o0 + 4];
        const v4h b1l = *(const v4h*)&segB[o1], b1h = *(const v4h*)&segB[o1 + 4];
        #pragma unroll
        for (int j = 0; j < 4; ++j) {
            A0A[j] = a0l[j]; A0A[4 + j] = a0h[j];
            A1A[j] = a1l[j]; A1A[4 + j] = a1h[j];
            A0B[j] = b0l[j]; A0B[4 + j] = b0h[j];
            A1B[j] = b1l[j]; A1B[4 + j] = b1h[j];
        }
    }
    if (q == 2) { A1A[2] = (_Float16)1.0f; A1B[2] = (_Float16)1.0f; }   // k=50: bias row
    #pragma unroll
    for (int t = 0; t < 4; ++t) {
        const v8h bf0 = wsv[W1_OFF + t * 64 + lane];
        const v8h bf1 = wsv[W1_OFF + 256 + t * 64 + lane];
        v4f cA = __builtin_amdgcn_mfma_f32_16x16x32_f16(bf0, A0A, (v4f)(0.0f), 0, 0, 0);
        cA = __builtin_amdgcn_mfma_f32_16x16x32_f16(bf1, A1A, cA, 0, 0, 0);
        v4f cB = __builtin_amdgcn_mfma_f32_16x16x32_f16(bf0, A0B, (v4f)(0.0f), 0, 0, 0);
        cB = __builtin_amdgcn_mfma_f32_16x16x32_f16(bf1, A1B, cB, 0, 0, 0);
        v4h pA, pB;
        #pragma unroll
        for (int rg = 0; rg < 4; ++rg) {
            pA[rg] = (_Float16)fast_tanh(cA[rg]);
            pB[rg] = (_Float16)fast_tanh(cB[rg]);
        }
        const int o = l15 * HS + t * 16 + q * 4;
        *(v4h*)&segA[o] = pA;
        *(v4h*)&segB[o] = pB;
    }

    // ---- phase 3 h2-frags (reload, b64 pairs) ----
    {
        const int o0 = l15 * HS + q * 8;
        const int o1 = l15 * HS + 32 + q * 8;
        const v4h a0l = *(const v4h*)&segA[o0], a0h = *(const v4h*)&segA[o0 + 4];
        const v4h a1l = *(const v4h*)&segA[o1], a1h = *(const v4h*)&segA[o1 + 4];
        const v4h b0l = *(const v4h*)&segB[o0], b0h = *(const v4h*)&segB[o0 + 4];
        const v4h b1l = *(const v4h*)&segB[o1], b1h = *(const v4h*)&segB[o1 + 4];
        #pragma unroll
        for (int j = 0; j < 4; ++j) {
            A0A[j] = a0l[j]; A0A[4 + j] = a0h[j];
            A1A[j] = a1l[j]; A1A[4 + j] = a1h[j];
            A0B[j] = b0l[j]; A0B[4 + j] = b0h[j];
            A1B[j] = b1l[j]; A1B[4 + j] = b1h[j];
        }
    }
    if (q == 2) { A1A[2] = (_Float16)1.0f; A1B[2] = (_Float16)1.0f; }   // k=50: bias row

    float ldacc = 0.0f;

    // ---- phase 3 first half: dims 0-3 (t = 0..7) -> slots 0..3, stride SROW=132 ----
    #pragma unroll 2
    for (int t = 0; t < 8; ++t) {
        const v8h bf0 = wsv[WC_OFF + t * 64 + lane];
        const v8h bf1 = wsv[WC_OFF + 1024 + t * 64 + lane];
        v4f cA = __builtin_amdgcn_mfma_f32_16x16x32_f16(bf0, A0A, (v4f)(0.0f), 0, 0, 0);
        cA = __builtin_amdgcn_mfma_f32_16x16x32_f16(bf1, A1A, cA, 0, 0, 0);
        v4f cB = __builtin_amdgcn_mfma_f32_16x16x32_f16(bf0, A0B, (v4f)(0.0f), 0, 0, 0);
        cB = __builtin_amdgcn_mfma_f32_16x16x32_f16(bf1, A1B, cB, 0, 0, 0);
        v4h pA, pB;
        #pragma unroll
        for (int rg = 0; rg < 4; ++rg) { pA[rg] = (_Float16)cA[rg]; pB[rg] = (_Float16)cB[rg]; }
        const int o = l15 * SROW + t * 16 + q * 4;   // byte = l15*264 + t*32 + q*8 (8-B aligned)
        *(v4h*)&segA[o] = pA;
        *(v4h*)&segB[o] = pB;
    }

    // ---- epilogue tasks tt=0 (d = q): in-order DS reads precede second-half overwrites ----
    spline_task(segA, l15 * SROW + q * 32, uA0, R0 + l15, q, out, ldacc);
    spline_task(segB, l15 * SROW + q * 32, uB0, R0 + 16 + l15, q, out, ldacc);

    // ---- phase 3 second half: dims 4-7 (t = 8..15) -> SAME slots 0..3 (buffer reuse) ----
    #pragma unroll 2
    for (int t = 8; t < 16; ++t) {
        const v8h bf0 = wsv[WC_OFF + t * 64 + lane];
        const v8h bf1 = wsv[WC_OFF + 1024 + t * 64 + lane];
        v4f cA = __builtin_amdgcn_mfma_f32_16x16x32_f16(bf0, A0A, (v4f)(0.0f), 0, 0, 0);
        cA = __builtin_amdgcn_mfma_f32_16x16x32_f16(bf1, A1A, cA, 0, 0, 0);
        v4f cB = __builtin_amdgcn_mfma_f32_16x16x32_f16(bf0, A0B, (v4f)(0.0f), 0, 0, 0);
        cB = __builtin_amdgcn_mfma_f32_16x16x32_f16(bf1, A1B, cB, 0, 0, 0);
        v4h pA, pB;
        #pragma unroll
        for (int rg = 0; rg < 4; ++rg) { pA[rg] = (_Float16)cA[rg]; pB[rg] = (_Float16)cB[rg]; }
        const int o = l15 * SROW + (t - 8) * 16 + q * 4;
        *(v4h*)&segA[o] = pA;
        *(v4h*)&segB[o] = pB;
    }

    // ---- epilogue tasks tt=1 (d = q+4, same slots) ----
    spline_task(segA, l15 * SROW + q * 32, uA1, R0 + l15, q + 4, out, ldacc);
    spline_task(segB, l15 * SROW + q * 32, uB1, R0 + 16 + l15, q + 4, out, ldacc);

    // ---- logdet: wave shuffle-reduce -> slot-spread atomics (64 slots) ----
    #pragma unroll
    for (int off = 32; off > 0; off >>= 1) ldacc += __shfl_down(ldacc, off);
    if (lane == 0) atomicAdd(&slots[waveId & 63], ldacc);
}

// ---- finish: sum the 64 partial slots into the scalar logdet output ----
__global__ void nsf_finish(const float* __restrict__ slots, float* __restrict__ ldp) {
    float v = slots[threadIdx.x];
    #pragma unroll
    for (int off = 32; off > 0; off >>= 1) v += __shfl_down(v, off);
    if (threadIdx.x == 0) *ldp = v;
}

extern "C" void kernel_launch(void* const* d_in, const int* in_sizes, int n_in,
                              void* d_out, int out_size, void* d_ws, size_t ws_size,
                              hipStream_t stream) {
    const float* x  = (const float*)d_in[0];
    const float* w0 = (const float*)d_in[1];
    const float* b0 = (const float*)d_in[2];
    const float* w1 = (const float*)d_in[3];
    const float* b1 = (const float*)d_in[4];
    const float* ww = (const float*)d_in[5];
    const float* bw = (const float*)d_in[6];
    const float* wh = (const float*)d_in[7];
    const float* bh = (const float*)d_in[8];
    const float* wd = (const float*)d_in[9];
    const float* bd = (const float*)d_in[10];

    float* out = (float*)d_out;
    float* ldp = out + (size_t)NROWS * 16;   // scalar logdet sum slot
    v8h* wsv = (v8h*)d_ws;                   // 45 KB packed B-fragments (bias folded)
    float* wsf = (float*)d_ws;               // f32 view for slots
    float* slots = wsf + SLOTS_OFF;

    hipLaunchKernelGGL(nsf_prep, dim3((FRAG_TOTAL + 255) / 256), dim3(256), 0, stream,
                       w0, b0, w1, b1, ww, bw, wh, bh, wd, bd, wsv, wsf);
    hipLaunchKernelGGL(nsf_main_v8, dim3(NROWS / 64), dim3(128), 0, stream,
                       x, wsv, out, slots);
    hipLaunchKernelGGL(nsf_finish, dim3(1), dim3(64), 0, stream, slots, ldp);
}